// Round 15
// baseline (762.901 us; speedup 1.0000x reference)
//
#include <hip/hip_runtime.h>
#include <math.h>

#define TT   512
#define BB   64
#define EMBD 512
#define HIDD 512

typedef _Float16 half2v __attribute__((ext_vector_type(2)));
typedef _Float16 half8  __attribute__((ext_vector_type(8)));
typedef float    f32x4  __attribute__((ext_vector_type(4)));

__device__ __forceinline__ float fdot2(unsigned a, unsigned b, float c) {
  half2v av = __builtin_bit_cast(half2v, a);
  half2v bv = __builtin_bit_cast(half2v, b);
  return __builtin_amdgcn_fdot2(av, bv, c, false);
}

__device__ __forceinline__ float fast_tanh(float x) {
  float e = __expf(2.0f * x);
  return 1.0f - 2.0f * __builtin_amdgcn_rcpf(e + 1.0f);
}

__device__ __forceinline__ unsigned pack2(float a, float b) {
  half2v hv; hv.x = (_Float16)a; hv.y = (_Float16)b;
  return __builtin_bit_cast(unsigned, hv);
}

__device__ __forceinline__ uint4 pack8(float4 f0, float4 f1) {
  uint4 u;
  u.x = pack2(f0.x, f0.y); u.y = pack2(f0.z, f0.w);
  u.z = pack2(f1.x, f1.y); u.w = pack2(f1.z, f1.w);
  return u;
}

// ---------------------------------------------------------------------------
// K0: repack fp32 W1h -> fp16 chunks for the v11/v12 wave-split-k mapping.
// elman thread tid: w=tid>>6 (q=w&3, hh=w>>2), l=tid&63.
// chunk c (0..63): jo=c&3, kq=c>>2. Covers j=256*hh+4*l+jo,
// k=128*q+8*kq..+8, packed as 4 dwords of (even,odd) fp16 pairs.
// ---------------------------------------------------------------------------
__global__ __launch_bounds__(256) void repack_w1h(
    const float* __restrict__ W1, uint4* __restrict__ wp)
{
  const int gid = blockIdx.x * 256 + threadIdx.x;   // 0..32767
  const int c   = gid >> 9;
  const int tid = gid & 511;
  const int w = tid >> 6, l = tid & 63;
  const int q = w & 3, hh = w >> 2;
  const int jo = c & 3, kq = c >> 2;
  const int j  = 256 * hh + 4 * l + jo;
  const int k0 = 128 * q + 8 * kq;
  const float* src = W1 + (size_t)j * (2 * EMBD) + EMBD + k0;
  unsigned r[4];
#pragma unroll
  for (int p = 0; p < 4; p++) r[p] = pack2(src[2 * p], src[2 * p + 1]);
  uint4 u; u.x = r[0]; u.y = r[1]; u.z = r[2]; u.w = r[3];
  wp[gid] = u;
}

// ---------------------------------------------------------------------------
// K1: px via fp16 MFMA (proven r12/r13: ~50 us, MFMA-active).
// ---------------------------------------------------------------------------
__global__ __launch_bounds__(256, 1) void px_mfma(
    const int* __restrict__ xx, const float* __restrict__ emb,
    const float* __restrict__ W1, const float* __restrict__ b1,
    float* __restrict__ px)
{
  __shared__ uint4 At[128 * 16];     // 32 KB: 128 rows x 256B (16 slots)
  __shared__ uint4 Bt[256 * 16];     // 64 KB: 256 rows x 256B
  __shared__ int stok[128];

  const int tid = threadIdx.x;
  const int wv  = tid >> 6, l = tid & 63;
  const int m0  = blockIdx.x * 128;
  const int j0  = blockIdx.y * 256;

  if (tid < 128) stok[tid] = xx[m0 + tid];

  f32x4 acc[8][4];
#pragma unroll
  for (int q = 0; q < 4; q++) {
    const float bc = b1[j0 + wv * 64 + 16 * q + (l & 15)];
#pragma unroll
    for (int i = 0; i < 8; i++) { acc[i][q].x = bc; acc[i][q].y = bc; acc[i][q].z = bc; acc[i][q].w = bc; }
  }

  for (int kc = 0; kc < 4; kc++) {
    __syncthreads();
    {
      const int r = tid >> 1, h = tid & 1;
      const float4* s4 = (const float4*)(emb + (size_t)stok[r] * EMBD + kc * 128 + h * 64);
#pragma unroll
      for (int i = 0; i < 8; i++)
        At[r * 16 + ((8 * h + i) ^ (r & 15))] = pack8(s4[2 * i], s4[2 * i + 1]);
      const float4* t4 = (const float4*)(W1 + (size_t)(j0 + tid) * (2 * EMBD) + kc * 128);
#pragma unroll
      for (int i = 0; i < 16; i++)
        Bt[tid * 16 + (i ^ (tid & 15))] = pack8(t4[2 * i], t4[2 * i + 1]);
    }
    __syncthreads();

#pragma unroll
    for (int ks = 0; ks < 4; ks++) {
      const int so = ks * 4 + (l >> 4);
      half8 a[8], bfr[4];
#pragma unroll
      for (int i = 0; i < 8; i++) {
        const int ra = 16 * i + (l & 15);
        a[i] = __builtin_bit_cast(half8, At[ra * 16 + (so ^ (ra & 15))]);
      }
#pragma unroll
      for (int q = 0; q < 4; q++) {
        const int rb = wv * 64 + 16 * q + (l & 15);
        bfr[q] = __builtin_bit_cast(half8, Bt[rb * 16 + (so ^ (rb & 15))]);
      }
#pragma unroll
      for (int i = 0; i < 8; i++)
#pragma unroll
        for (int q = 0; q < 4; q++)
          acc[i][q] = __builtin_amdgcn_mfma_f32_16x16x32_f16(a[i], bfr[q], acc[i][q], 0, 0, 0);
    }
  }

#pragma unroll
  for (int i = 0; i < 8; i++) {
    const int mrow = m0 + 16 * i + (l >> 4) * 4;
#pragma unroll
    for (int q = 0; q < 4; q++) {
      const int col = j0 + wv * 64 + 16 * q + (l & 15);
      float* dst = px + (size_t)mrow * HIDD + col;
      dst[0 * HIDD] = acc[i][q].x;
      dst[1 * HIDD] = acc[i][q].y;
      dst[2 * HIDD] = acc[i][q].z;
      dst[3 * HIDD] = acc[i][q].w;
    }
  }
}

// ---------------------------------------------------------------------------
// K2: recurrence v12 = v11 (r13, proven: 745 us, 0 bank conflicts) +
//   (a) amdgpu_num_vgpr(256): grant the full 2-wave arch-VGPR budget so
//       all 49 weight chunks live in true VGPRs (no AGPR round-trips);
//   (b) kq15 LDS chunks prefetched at step top (consumed last).
// Mapping unchanged: wave w: k-quarter q=w&3, j-half hh=w>>2; lane l:
// j=256*hh+4*l+{0..3}; h reads wave-uniform broadcasts; parts merge;
// linear b16 h store; two barriers/step.
// ---------------------------------------------------------------------------
#define DOT4(HH, W0, W1v, W2v, W3v) do {                                    \
    const uint4 hh = (HH);                                                  \
    a0=fdot2((W0).x,hh.x,a0);  a0=fdot2((W0).y,hh.y,a0);                    \
    a0=fdot2((W0).z,hh.z,a0);  a0=fdot2((W0).w,hh.w,a0);                    \
    a1=fdot2((W1v).x,hh.x,a1); a1=fdot2((W1v).y,hh.y,a1);                   \
    a1=fdot2((W1v).z,hh.z,a1); a1=fdot2((W1v).w,hh.w,a1);                   \
    a2=fdot2((W2v).x,hh.x,a2); a2=fdot2((W2v).y,hh.y,a2);                   \
    a2=fdot2((W2v).z,hh.z,a2); a2=fdot2((W2v).w,hh.w,a2);                   \
    a3=fdot2((W3v).x,hh.x,a3); a3=fdot2((W3v).y,hh.y,a3);                   \
    a3=fdot2((W3v).z,hh.z,a3); a3=fdot2((W3v).w,hh.w,a3);                   \
  } while (0)

__attribute__((amdgpu_flat_work_group_size(512, 512),
               amdgpu_waves_per_eu(2), amdgpu_num_vgpr(256)))
__global__ void elman_v12(
    const uint4* __restrict__ wp, const float* __restrict__ px,
    const float* __restrict__ W2, const float* __restrict__ b2,
    float* __restrict__ out)
{
  __shared__ uint4 wlds[15 * 512];          // 120 KB static (c 49..63)
  __shared__ __align__(16) unsigned short hbuf[HIDD];   // 1 KB fp16 h
  __shared__ float parts[4][HIDD];          // 8 KB quarter partials
  __shared__ float red[2][8];

  const int b   = blockIdx.x;
  const int tid = threadIdx.x;
  const int w   = tid >> 6, l = tid & 63;
  const int q   = w & 3;                    // this wave's k-quarter
  const int hh  = w >> 2;                   // this wave's j-half
  const int jb  = 256 * hh + 4 * l;         // first of this thread's 4 j

  // prologue: 49 reg chunks + 15 LDS chunks (all coalesced)
  uint4 wr[49];
#pragma unroll
  for (int i = 0; i < 49; i++) wr[i] = wp[(size_t)i * 512 + tid];
#pragma unroll
  for (int i = 0; i < 15; i++) wlds[i * 512 + tid] = wp[(size_t)(49 + i) * 512 + tid];
  if (tid < 64) ((uint4*)hbuf)[tid] = make_uint4(0u, 0u, 0u, 0u);
  __syncthreads();

  const uint4* hq = (const uint4*)hbuf + 16 * q;   // wave-uniform base
  const float* pxj = px + (size_t)b * TT * HIDD + tid;
  float rmq = -INFINITY;

  for (int t = 0; t < TT; t++) {
    // early issues: this thread's px + the kq15 LDS chunks (consumed last)
    float pxs = pxj[(size_t)t * HIDD];
    const uint4 p0 = wlds[11 * 512 + tid];
    const uint4 p1 = wlds[12 * 512 + tid];
    const uint4 p2 = wlds[13 * 512 + tid];
    const uint4 p3 = wlds[14 * 512 + tid];

    float a0 = 0.f, a1 = 0.f, a2 = 0.f, a3 = 0.f;

    // kq 0..11: register weights (h reads are wave-uniform broadcasts)
#pragma unroll
    for (int kq = 0; kq < 12; kq++)
      DOT4(hq[kq], wr[4 * kq + 0], wr[4 * kq + 1], wr[4 * kq + 2], wr[4 * kq + 3]);
    // kq 12: c48 reg + c49..51 LDS
    DOT4(hq[12], wr[48],
         wlds[0 * 512 + tid], wlds[1 * 512 + tid], wlds[2 * 512 + tid]);
    // kq 13..14: LDS
    DOT4(hq[13], wlds[3 * 512 + tid], wlds[4 * 512 + tid],
         wlds[5 * 512 + tid], wlds[6 * 512 + tid]);
    DOT4(hq[14], wlds[7 * 512 + tid], wlds[8 * 512 + tid],
         wlds[9 * 512 + tid], wlds[10 * 512 + tid]);
    // kq 15: prefetched at step top
    DOT4(hq[15], p0, p1, p2, p3);

    // publish quarter partials: coalesced float4 per thread
    *(float4*)&parts[q][jb] = make_float4(a0, a1, a2, a3);
    __syncthreads();

    // finalize: thread tid owns j = tid
    float s = parts[0][tid] + parts[1][tid] + parts[2][tid] + parts[3][tid] + pxs;
    float hv = fast_tanh(s);
    rmq = fmaxf(rmq, hv);
    _Float16 hf = (_Float16)hv;
    hbuf[tid] = __builtin_bit_cast(unsigned short, hf);
    if (t == TT - 1)
      out[2 * BB + (size_t)b * HIDD + tid] = hv;
    __syncthreads();
  }

  // pooled max -> logits (rmq is per-thread for j = tid)
  {
    float q0 = rmq * W2[tid];
    float q1 = rmq * W2[HIDD + tid];
#pragma unroll
    for (int off = 32; off; off >>= 1) {
      q0 += __shfl_down(q0, off);
      q1 += __shfl_down(q1, off);
    }
    if (l == 0) { red[0][w] = q0; red[1][w] = q1; }
  }
  __syncthreads();
  if (tid < 2) {
    float s = b2[tid];
#pragma unroll
    for (int i = 0; i < 8; i++) s += red[tid][i];
    out[b * 2 + tid] = s;
  }
}

// ---------------------------------------------------------------------------
extern "C" void kernel_launch(void* const* d_in, const int* in_sizes, int n_in,
                              void* d_out, int out_size, void* d_ws, size_t ws_size,
                              hipStream_t stream)
{
  const int*   x   = (const int*)d_in[0];
  const float* emb = (const float*)d_in[1];
  const float* W1  = (const float*)d_in[2];
  const float* b1  = (const float*)d_in[3];
  const float* W2  = (const float*)d_in[4];
  const float* b2  = (const float*)d_in[5];
  float* out = (float*)d_out;
  char* ws = (char*)d_ws;

  uint4* wp = (uint4*)ws;                        // 512 KB repacked fp16 W1h
  float* px = (float*)(ws + (1 << 19));          // 64 MB
  const size_t need = (size_t)(1 << 19) + (size_t)BB * TT * HIDD * sizeof(float);
  if (ws_size < need) return;

  repack_w1h<<<128, 256, 0, stream>>>(W1, wp);
  px_mfma<<<dim3(TT * BB / 128, HIDD / 256), 256, 0, stream>>>(x, emb, W1, b1, px);
  elman_v12<<<dim3(BB), dim3(512), 0, stream>>>(wp, px, W2, b2, out);
}